// Round 11
// baseline (4640.984 us; speedup 1.0000x reference)
//
#include <hip/hip_runtime.h>

#define BB 64
#define HH 1024
#define TT 512
#define GG 4096
#define VV 256
#define NBLK 256
#define BPG 128   // blocks per group
#define BG  32    // batches per group
#define UPB 8     // units per block

typedef __attribute__((ext_vector_type(8))) short short8;
typedef __attribute__((ext_vector_type(4))) float f32x4;
typedef __attribute__((ext_vector_type(4))) unsigned uint32x4;

__device__ __forceinline__ unsigned short f2bf(float f) {
  unsigned u = __float_as_uint(f);
  u += 0x7fffu + ((u >> 16) & 1u);
  return (unsigned short)(u >> 16);
}

__device__ __forceinline__ float sigf(float x) { return 1.0f / (1.0f + __expf(-x)); }
__device__ __forceinline__ float tanhfast(float x) {
  float t = __expf(2.0f * x);
  return (t - 1.0f) / (t + 1.0f);
}

__device__ __forceinline__ unsigned pkmax(unsigned a, unsigned b) {
  unsigned d;
  asm("v_pk_max_u16 %0, %1, %2" : "=v"(d) : "v"(a), "v"(b));
  return d;
}

__device__ __forceinline__ short8 as_s8(uint32x4 v) {
  short8 r;
  __builtin_memcpy(&r, &v, 16);
  return r;
}

// ---------------------------------------------------------------------------
// Prepass 1: P0[v][unit][gate] = (embed @ Wi[0] + b[0]) re-packed, fp32.
// ---------------------------------------------------------------------------
__global__ void __launch_bounds__(256, 1)
p0_kernel(const float* __restrict__ embed, const float* __restrict__ Wi,
          const float* __restrict__ bias, float* __restrict__ P0p)
{
  __shared__ float elds[16][1024];  // 64 KB
  const int tid = threadIdx.x;
  const int vt = blockIdx.x >> 4;
  const int ct = blockIdx.x & 15;
  for (int i = tid; i < 16 * 1024; i += 256)
    elds[i >> 10][i & 1023] = embed[((vt * 16 + (i >> 10)) << 10) + (i & 1023)];
  __syncthreads();
  const int c = ct * 256 + tid;           // column in [0,4096)
  float acc[16];
#pragma unroll
  for (int v = 0; v < 16; ++v) acc[v] = 0.f;
  for (int kk = 0; kk < 1024; ++kk) {
    const float wv = Wi[kk * GG + c];     // coalesced
#pragma unroll
    for (int v = 0; v < 16; ++v) acc[v] = fmaf(elds[v][kk], wv, acc[v]);
  }
  const int u = c & 1023, g = c >> 10;
  const float bv = bias[c];               // b[0][c]
#pragma unroll
  for (int v = 0; v < 16; ++v)
    P0p[(((size_t)(vt * 16 + v) * HH) + u) * 4 + g] = acc[v] + bv;
}

// ---------------------------------------------------------------------------
// Prepass 2: pack Wproj into bf16 MFMA B-fragments; pack b[1] as [unit][gate].
// ---------------------------------------------------------------------------
__global__ void pack_misc(const float* __restrict__ Wproj, const float* __restrict__ bias,
                          unsigned short* __restrict__ Wppk, float* __restrict__ b1p)
{
  const int t = blockIdx.x * 256 + threadIdx.x;
  if (t < 16 * 32 * 64) {
    const int lane = t & 63;
    const int kt = (t >> 6) & 31;
    const int nt = t >> 11;
    const int v = nt * 16 + (lane & 15);
    const int kb = kt * 32 + (lane >> 4) * 8;
    short8 fr;
#pragma unroll
    for (int e = 0; e < 8; ++e)
      fr[e] = (short)f2bf(Wproj[(size_t)(kb + e) * VV + v]);
    *(short8*)(Wppk + (size_t)t * 8) = fr;
  }
  if (t < 4096)
    b1p[t] = bias[GG + (t & 3) * HH + (t >> 2)];  // b1p[u*4+g] = b[1][g*1024+u]
}

// ---------------------------------------------------------------------------
// Persistent LSTM kernel, 2 decoupled batch-groups, NO grid barrier.
// h buffers are write-once (513 rotating slots each), pre-poisoned to 0xFFFF
// (bf16 NaN — unreachable for |tanh|<1 outputs). Readers poll their own
// MFMA A-operand data with sc0 sc1 loads until no u16 is poison (pk_max_u16
// tree); per-stage retry masks re-issue only straggler stages. The first
// clean poll IS the read: signal and data fused into one coherent round.
// Stores remain agent write-through (visible at L3, where polls read).
// Retry loop is BOUNDED (safety valve vs GPU hang) with s_sleep(8) backoff.
// ---------------------------------------------------------------------------
__global__ void __launch_bounds__(256, 1)
lstm_persist(const float* __restrict__ Wi, const float* __restrict__ Wh,
             const int* __restrict__ idx, const float* __restrict__ P0p,
             const float* __restrict__ b1p,
             unsigned short* __restrict__ h0r, unsigned short* __restrict__ hs)
{
  __shared__ short wlds[32][2][64][8];      // 64 KB: Wh0 [kt][nt][lane][8]
  __shared__ float zbuf[2][4][32][36];      // 36 KB: [layer][wave][row][col+pad]

  const int tid = threadIdx.x;
  const int lane = tid & 63;
  const int w = tid >> 6;
  const int bid = blockIdx.x;
  const int g = bid & 1;          // group (~XCD parity)
  const int ub = bid >> 1;        // unit-block 0..127
  const int w8 = w * 8;

  // ---- one-time: Wh0 fragments -> LDS; Wi1, Wh1 fragments -> VGPRs ----
  short8 wi1r[8][2], wh1r[8][2];
  {
    const int arow16 = lane & 15;
    const int kb4 = (lane >> 4) * 8;
    for (int kk = 0; kk < 8; ++kk) {
      const int kbase = (w8 + kk) * 32 + kb4;
      for (int nt = 0; nt < 2; ++nt) {
        const int cl = nt * 16 + arow16;
        const int cg = (cl & 3) * HH + ub * UPB + (cl >> 2);
        short8 fr;
#pragma unroll
        for (int e = 0; e < 8; ++e)
          fr[e] = (short)f2bf(Wh[(size_t)(kbase + e) * GG + cg]);
        *(short8*)(&wlds[w8 + kk][nt][lane][0]) = fr;
      }
    }
    const float* srcWi1 = Wi + (size_t)HH * GG;
    const float* srcWh1 = Wh + (size_t)HH * GG;
#pragma unroll
    for (int kk = 0; kk < 8; ++kk) {
      const int kbase = (w8 + kk) * 32 + kb4;
#pragma unroll
      for (int nt = 0; nt < 2; ++nt) {
        const int cl = nt * 16 + arow16;
        const int cg = (cl & 3) * HH + ub * UPB + (cl >> 2);
        short8 fa, fb;
#pragma unroll
        for (int e = 0; e < 8; ++e) {
          fa[e] = (short)f2bf(srcWi1[(size_t)(kbase + e) * GG + cg]);
          fb[e] = (short)f2bf(srcWh1[(size_t)(kbase + e) * GG + cg]);
        }
        wi1r[kk][nt] = fa;
        wh1r[kk][nt] = fb;
      }
    }
  }
  __syncthreads();

  // elementwise ownership: thread -> (group-local batch ebl, local unit eu)
  const int ebl = tid >> 3;            // 0..31
  const int eu = tid & 7;              // 0..7
  const int ebg = g * BG + ebl;        // global batch row
  const int egu = ub * UPB + eu;       // global unit
  float c0 = 0.f, c1 = 0.f;
  const float4 b1v = *(const float4*)(b1p + egu * 4);

  const int arow = lane & 15;
  const int koff = (lane >> 4) * 8;

  // A row offsets (elements): mt0 rows g*32+arow, mt1 rows +16
  const int ro0 = (g * BG + arow) * HH + w * 256 + koff;
  const int ro1 = (g * BG + 16 + arow) * HH + w * 256 + koff;

  // ---- gate-input software prefetch (idx -> P0p row), one tick ahead ----
  int v_pf = idx[ebg * TT];                                        // k = 0
  float4 p_pf = *(const float4*)(P0p + ((size_t)v_pf * HH + egu) * 4);

#define GLD(dst, addr)                                                         \
  asm volatile("global_load_dwordx4 %0, %1, off sc0 sc1"                       \
               : "=&v"(dst) : "v"(addr));

#define ISSUE4(s)                                                              \
  GLD(ring[s][0], p00 + (s) * 32)                                              \
  GLD(ring[s][1], p01 + (s) * 32)                                              \
  GLD(ring[s][2], p10 + (s) * 32)                                              \
  GLD(ring[s][3], p11 + (s) * 32)

#define WAITV0                                                                 \
  asm volatile("s_waitcnt vmcnt(0)" ::: "memory");                             \
  __builtin_amdgcn_sched_barrier(0);

#define LDB(s, nt) (*(const short8*)(&wlds[w8 + (s)][nt][lane][0]))

#define MFMA_STAGE(s)                                                                                 \
  a0[0][0] = __builtin_amdgcn_mfma_f32_16x16x32_bf16(as_s8(ring[s][0]), f0a, a0[0][0], 0, 0, 0);      \
  a0[0][1] = __builtin_amdgcn_mfma_f32_16x16x32_bf16(as_s8(ring[s][0]), f0b, a0[0][1], 0, 0, 0);      \
  a0[1][0] = __builtin_amdgcn_mfma_f32_16x16x32_bf16(as_s8(ring[s][1]), f0a, a0[1][0], 0, 0, 0);      \
  a0[1][1] = __builtin_amdgcn_mfma_f32_16x16x32_bf16(as_s8(ring[s][1]), f0b, a0[1][1], 0, 0, 0);      \
  a1[0][0] = __builtin_amdgcn_mfma_f32_16x16x32_bf16(as_s8(ring[s][0]), wi1r[s][0], a1[0][0], 0, 0, 0); \
  a1[0][1] = __builtin_amdgcn_mfma_f32_16x16x32_bf16(as_s8(ring[s][0]), wi1r[s][1], a1[0][1], 0, 0, 0); \
  a1[1][0] = __builtin_amdgcn_mfma_f32_16x16x32_bf16(as_s8(ring[s][1]), wi1r[s][0], a1[1][0], 0, 0, 0); \
  a1[1][1] = __builtin_amdgcn_mfma_f32_16x16x32_bf16(as_s8(ring[s][1]), wi1r[s][1], a1[1][1], 0, 0, 0); \
  a1[0][0] = __builtin_amdgcn_mfma_f32_16x16x32_bf16(as_s8(ring[s][2]), wh1r[s][0], a1[0][0], 0, 0, 0); \
  a1[0][1] = __builtin_amdgcn_mfma_f32_16x16x32_bf16(as_s8(ring[s][2]), wh1r[s][1], a1[0][1], 0, 0, 0); \
  a1[1][0] = __builtin_amdgcn_mfma_f32_16x16x32_bf16(as_s8(ring[s][3]), wh1r[s][0], a1[1][0], 0, 0, 0); \
  a1[1][1] = __builtin_amdgcn_mfma_f32_16x16x32_bf16(as_s8(ring[s][3]), wh1r[s][1], a1[1][1], 0, 0, 0);

#define STAGE(s)                                                               \
  {                                                                            \
    const short8 n0a = LDB(((s) + 1) & 7, 0);                                  \
    const short8 n0b = LDB(((s) + 1) & 7, 1);                                  \
    MFMA_STAGE(s)                                                              \
    f0a = n0a; f0b = n0b;                                                      \
  }

  for (int k = 0; k <= TT; ++k) {
    const unsigned short* A01 = h0r + (size_t)k * (BB * HH);                 // h0(k-1)
    const unsigned short* A2  = hs + (size_t)(k > 0 ? (k - 1) : 0) * (BB * HH); // h1(k-2)

    const unsigned short* p00 = A01 + ro0;
    const unsigned short* p01 = A01 + ro1;
    const unsigned short* p10 = A2 + ro0;
    const unsigned short* p11 = A2 + ro1;

    uint32x4 ring[8][4];

    // ---- data-poll: load A operands until no u16 is poison (0xFFFF) ----
    {
      unsigned need = 0xFFu;
      int tries = 0;
      for (;;) {
        if (need & 0x01u) { ISSUE4(0) }
        if (need & 0x02u) { ISSUE4(1) }
        if (need & 0x04u) { ISSUE4(2) }
        if (need & 0x08u) { ISSUE4(3) }
        if (need & 0x10u) { ISSUE4(4) }
        if (need & 0x20u) { ISSUE4(5) }
        if (need & 0x40u) { ISSUE4(6) }
        if (need & 0x80u) { ISSUE4(7) }
        WAITV0
        unsigned nneed = 0;
#pragma unroll
        for (int s = 0; s < 8; ++s)
          if (need & (1u << s)) {
            unsigned mm = 0;
#pragma unroll
            for (int j = 0; j < 4; ++j) {
              const uint32x4 v = ring[s][j];
              mm = pkmax(mm, pkmax(pkmax(v[0], v[1]), pkmax(v[2], v[3])));
            }
            const bool bad = ((mm & 0xFFFFu) == 0xFFFFu) || ((mm >> 16) == 0xFFFFu);
            if (__any(bad)) nneed |= (1u << s);
          }
        need = nneed;
        if (!need) break;
        if (++tries > (1 << 17)) break;   // safety valve: never hang the GPU
        __builtin_amdgcn_s_sleep(8);
      }
      __builtin_amdgcn_sched_barrier(0);
    }

    f32x4 a0[2][2], a1[2][2];
#pragma unroll
    for (int mt = 0; mt < 2; ++mt)
#pragma unroll
      for (int nt = 0; nt < 2; ++nt) {
        a0[mt][nt] = f32x4{0.f, 0.f, 0.f, 0.f};
        a1[mt][nt] = f32x4{0.f, 0.f, 0.f, 0.f};
      }

    short8 f0a = LDB(0, 0), f0b = LDB(0, 1);
    STAGE(0) STAGE(1) STAGE(2) STAGE(3)
    STAGE(4) STAGE(5) STAGE(6) STAGE(7)

    // ---- both layers' K-partials -> LDS ----
    {
      const int colb = lane & 15;
      const int r0w = (lane >> 4) * 4;
#pragma unroll
      for (int mt = 0; mt < 2; ++mt)
#pragma unroll
        for (int nt = 0; nt < 2; ++nt)
#pragma unroll
          for (int r = 0; r < 4; ++r) {
            zbuf[0][w][mt * 16 + r0w + r][nt * 16 + colb] = a0[mt][nt][r];
            zbuf[1][w][mt * 16 + r0w + r][nt * 16 + colb] = a1[mt][nt][r];
          }
    }
    __syncthreads();

    // ---- layer 0 reduce + gates + h0 store ----
    {
      float z0[4] = {0.f, 0.f, 0.f, 0.f};
#pragma unroll
      for (int ww = 0; ww < 4; ++ww) {
        const float4 pv = *(const float4*)(&zbuf[0][ww][ebl][eu * 4]);
        z0[0] += pv.x; z0[1] += pv.y; z0[2] += pv.z; z0[3] += pv.w;
      }
      if (k < TT) {
        const float gi = sigf(z0[0] + p_pf.x);
        const float gf = sigf(z0[1] + p_pf.y);
        const float gc = tanhfast(z0[2] + p_pf.z);
        const float go = sigf(z0[3] + p_pf.w);
        c0 = gf * c0 + gi * gc;
        __hip_atomic_store(&h0r[(size_t)(k + 1) * (BB * HH) + ebg * HH + egu],
                           f2bf(go * tanhfast(c0)),
                           __ATOMIC_RELAXED, __HIP_MEMORY_SCOPE_AGENT);
        if (k + 1 < TT) {   // prefetch next tick's gate inputs
          v_pf = idx[ebg * TT + k + 1];
          p_pf = *(const float4*)(P0p + ((size_t)v_pf * HH + egu) * 4);
        }
      }
    }

    // ---- layer 1 reduce + gates + h1 store ----
    if (k > 0) {
      float z1[4] = {0.f, 0.f, 0.f, 0.f};
#pragma unroll
      for (int ww = 0; ww < 4; ++ww) {
        const float4 pv = *(const float4*)(&zbuf[1][ww][ebl][eu * 4]);
        z1[0] += pv.x; z1[1] += pv.y; z1[2] += pv.z; z1[3] += pv.w;
      }
      const float gi = sigf(z1[0] + b1v.x);
      const float gf = sigf(z1[1] + b1v.y);
      const float gc = tanhfast(z1[2] + b1v.z);
      const float go = sigf(z1[3] + b1v.w);
      c1 = gf * c1 + gi * gc;
      __hip_atomic_store(&hs[(size_t)k * (BB * HH) + ebg * HH + egu],
                         f2bf(go * tanhfast(c1)),
                         __ATOMIC_RELAXED, __HIP_MEMORY_SCOPE_AGENT);
    }

    if (k == TT) break;

    // protect zbuf (and keep waves loosely together) before next tick
    __syncthreads();
  }
#undef GLD
#undef ISSUE4
#undef WAITV0
#undef LDB
#undef MFMA_STAGE
#undef STAGE
}

// ---------------------------------------------------------------------------
// Final projection: logits[b][t][v] = hs1[b][t][:] @ Wproj.  One block per t.
// ---------------------------------------------------------------------------
__global__ void __launch_bounds__(256, 1)
proj_kernel(const unsigned short* __restrict__ hs, const unsigned short* __restrict__ Wppk,
            float* __restrict__ out)
{
  __shared__ short blds[16][64][8];  // 16 KB: one kt-slice of packed Wproj
  const int tid = threadIdx.x;
  const int lane = tid & 63;
  const int w = tid >> 6;
  const int t = blockIdx.x;
  const unsigned short* A = hs + (size_t)(t + 1) * (BB * HH);
  f32x4 acc[16];
#pragma unroll
  for (int nt = 0; nt < 16; ++nt) acc[nt] = f32x4{0.f, 0.f, 0.f, 0.f};
  const int arow = w * 16 + (lane & 15);
  const int koff = (lane >> 4) * 8;
  for (int kt = 0; kt < 32; ++kt) {
    __syncthreads();
    for (int i = tid; i < 16 * 64; i += 256)
      *(short8*)(&blds[i >> 6][i & 63][0]) =
          *(const short8*)(Wppk + (size_t)(((i >> 6) * 32 + kt) * 64 + (i & 63)) * 8);
    __syncthreads();
    const short8 a = *(const short8*)(A + arow * HH + kt * 32 + koff);
#pragma unroll
    for (int nt = 0; nt < 16; ++nt) {
      const short8 bf = *(const short8*)(&blds[nt][lane][0]);
      acc[nt] = __builtin_amdgcn_mfma_f32_16x16x32_bf16(a, bf, acc[nt], 0, 0, 0);
    }
  }
#pragma unroll
  for (int nt = 0; nt < 16; ++nt) {
#pragma unroll
    for (int r = 0; r < 4; ++r) {
      const int bbv = w * 16 + (lane >> 4) * 4 + r;
      const int vv = nt * 16 + (lane & 15);
      out[((size_t)bbv * TT + t) * VV + vv] = acc[nt][r];
    }
  }
}

// ---------------------------------------------------------------------------
extern "C" void kernel_launch(void* const* d_in, const int* in_sizes, int n_in,
                              void* d_out, int out_size, void* d_ws, size_t ws_size,
                              hipStream_t stream)
{
  (void)in_sizes; (void)n_in; (void)out_size; (void)ws_size;
  const int* idx = (const int*)d_in[0];
  const float* embed = (const float*)d_in[1];
  const float* Wi = (const float*)d_in[2];
  const float* Wh = (const float*)d_in[3];
  const float* bias = (const float*)d_in[4];
  const float* Wproj = (const float*)d_in[5];
  float* out = (float*)d_out;

  char* ws = (char*)d_ws;
  size_t off = 0;
  unsigned short* h0r = (unsigned short*)(ws + off); off += 513ull * BB * HH * 2;     // ~64.1 MB (rotating h0)
  unsigned short* hs = (unsigned short*)(ws + off);  off += 513ull * BB * HH * 2;     // ~64.1 MB
  float* P0p = (float*)(ws + off);                  off += 256ull * HH * 4 * 4;       // 4 MB
  unsigned short* Wppk = (unsigned short*)(ws + off); off += 16ull * 32 * 64 * 8 * 2; // 512 KB
  float* b1p = (float*)(ws + off);                  off += 4096ull * 4;

  // poison h buffers (0xFFFF u16 = bf16 NaN, unreachable for tanh outputs);
  // slot 0 of each = initial state = 0
  hipMemsetAsync(h0r, 0xFF, 513ull * BB * HH * 2, stream);
  hipMemsetAsync(hs, 0xFF, 513ull * BB * HH * 2, stream);
  hipMemsetAsync(h0r, 0, (size_t)BB * HH * 2, stream);
  hipMemsetAsync(hs, 0, (size_t)BB * HH * 2, stream);

  p0_kernel<<<256, 256, 0, stream>>>(embed, Wi, bias, P0p);
  pack_misc<<<128, 256, 0, stream>>>(Wproj, bias, Wppk, b1p);

  lstm_persist<<<NBLK, 256, 0, stream>>>(Wi, Wh, idx, P0p, b1p, h0r, hs);

  proj_kernel<<<512, 256, 0, stream>>>(hs, Wppk, out);
}

// Round 12
// 4478.244 us; speedup vs baseline: 1.0363x; 1.0363x over previous
//
#include <hip/hip_runtime.h>

#define BB 64
#define HH 1024
#define TT 512
#define GG 4096
#define VV 256
#define NBLK 256
#define BPG 128   // blocks per group
#define BG  32    // batches per group
#define UPB 8     // units per block

typedef __attribute__((ext_vector_type(8))) short short8;
typedef __attribute__((ext_vector_type(4))) float f32x4;
typedef __attribute__((ext_vector_type(4))) unsigned uint32x4;

__device__ __forceinline__ unsigned short f2bf(float f) {
  unsigned u = __float_as_uint(f);
  u += 0x7fffu + ((u >> 16) & 1u);
  return (unsigned short)(u >> 16);
}

__device__ __forceinline__ float sigf(float x) { return 1.0f / (1.0f + __expf(-x)); }
__device__ __forceinline__ float tanhfast(float x) {
  float t = __expf(2.0f * x);
  return (t - 1.0f) / (t + 1.0f);
}

// ---------------------------------------------------------------------------
// Prepass 1: P0[v][unit][gate] = (embed @ Wi[0] + b[0]) re-packed, fp32.
// ---------------------------------------------------------------------------
__global__ void __launch_bounds__(256, 1)
p0_kernel(const float* __restrict__ embed, const float* __restrict__ Wi,
          const float* __restrict__ bias, float* __restrict__ P0p)
{
  __shared__ float elds[16][1024];  // 64 KB
  const int tid = threadIdx.x;
  const int vt = blockIdx.x >> 4;
  const int ct = blockIdx.x & 15;
  for (int i = tid; i < 16 * 1024; i += 256)
    elds[i >> 10][i & 1023] = embed[((vt * 16 + (i >> 10)) << 10) + (i & 1023)];
  __syncthreads();
  const int c = ct * 256 + tid;           // column in [0,4096)
  float acc[16];
#pragma unroll
  for (int v = 0; v < 16; ++v) acc[v] = 0.f;
  for (int kk = 0; kk < 1024; ++kk) {
    const float wv = Wi[kk * GG + c];     // coalesced
#pragma unroll
    for (int v = 0; v < 16; ++v) acc[v] = fmaf(elds[v][kk], wv, acc[v]);
  }
  const int u = c & 1023, g = c >> 10;
  const float bv = bias[c];               // b[0][c]
#pragma unroll
  for (int v = 0; v < 16; ++v)
    P0p[(((size_t)(vt * 16 + v) * HH) + u) * 4 + g] = acc[v] + bv;
}

// ---------------------------------------------------------------------------
// Prepass 2: pack Wproj into bf16 MFMA B-fragments; pack b[1] as [unit][gate].
// ---------------------------------------------------------------------------
__global__ void pack_misc(const float* __restrict__ Wproj, const float* __restrict__ bias,
                          unsigned short* __restrict__ Wppk, float* __restrict__ b1p)
{
  const int t = blockIdx.x * 256 + threadIdx.x;
  if (t < 16 * 32 * 64) {
    const int lane = t & 63;
    const int kt = (t >> 6) & 31;
    const int nt = t >> 11;
    const int v = nt * 16 + (lane & 15);
    const int kb = kt * 32 + (lane >> 4) * 8;
    short8 fr;
#pragma unroll
    for (int e = 0; e < 8; ++e)
      fr[e] = (short)f2bf(Wproj[(size_t)(kb + e) * VV + v]);
    *(short8*)(Wppk + (size_t)t * 8) = fr;
  }
  if (t < 4096)
    b1p[t] = bias[GG + (t & 3) * HH + (t >> 2)];  // b1p[u*4+g] = b[1][g*1024+u]
}

// ---------------------------------------------------------------------------
// Persistent LSTM kernel, 2 decoupled batch-groups, 8 waves/block (512 thr)
// = 2 waves/SIMD so intra-tick latencies overlap across waves. 1 block/CU
// (136 KB LDS). Group g = bid&1 owns batches [32g,32g+32); block owns 8
// units of both layers. Wh0 B-fragments in LDS (64 KB); Wi1+Wh1 in VGPRs
// (halved per-wave: K-split is now 8 x 128). h exchange: agent write-through
// stores + cached reads (XCD-L2 amortizes the broadcast; h slots rotate
// write-once so no stale-copy hazard) + group-local distributed-flag barrier.
// ---------------------------------------------------------------------------
__global__ void __launch_bounds__(512, 2)
lstm_persist(const float* __restrict__ Wi, const float* __restrict__ Wh,
             const int* __restrict__ idx, const float* __restrict__ P0p,
             const float* __restrict__ b1p,
             unsigned short* __restrict__ h0r, unsigned short* __restrict__ hs,
             unsigned* __restrict__ flags)
{
  __shared__ short wlds[32][2][64][8];      // 64 KB: Wh0 [kt][nt][lane][8]
  __shared__ float zbuf[2][8][32][36];      // 72 KB: [layer][wave][row][col+pad]

  const int tid = threadIdx.x;
  const int lane = tid & 63;
  const int w = tid >> 6;          // 0..7
  const int bid = blockIdx.x;
  const int g = bid & 1;           // group (~XCD parity)
  const int ub = bid >> 1;         // unit-block 0..127
  const int w4 = w * 4;            // this wave's first kt tile

  // ---- one-time: Wh0 fragments -> LDS; Wi1, Wh1 fragments -> VGPRs ----
  short8 wi1r[4][2], wh1r[4][2];
  {
    const int arow16 = lane & 15;
    const int kb4 = (lane >> 4) * 8;
    for (int kk = 0; kk < 4; ++kk) {
      const int kbase = (w4 + kk) * 32 + kb4;
      for (int nt = 0; nt < 2; ++nt) {
        const int cl = nt * 16 + arow16;
        const int cg = (cl & 3) * HH + ub * UPB + (cl >> 2);
        short8 fr;
#pragma unroll
        for (int e = 0; e < 8; ++e)
          fr[e] = (short)f2bf(Wh[(size_t)(kbase + e) * GG + cg]);
        *(short8*)(&wlds[w4 + kk][nt][lane][0]) = fr;
      }
    }
    const float* srcWi1 = Wi + (size_t)HH * GG;
    const float* srcWh1 = Wh + (size_t)HH * GG;
#pragma unroll
    for (int kk = 0; kk < 4; ++kk) {
      const int kbase = (w4 + kk) * 32 + kb4;
#pragma unroll
      for (int nt = 0; nt < 2; ++nt) {
        const int cl = nt * 16 + arow16;
        const int cg = (cl & 3) * HH + ub * UPB + (cl >> 2);
        short8 fa, fb;
#pragma unroll
        for (int e = 0; e < 8; ++e) {
          fa[e] = (short)f2bf(srcWi1[(size_t)(kbase + e) * GG + cg]);
          fb[e] = (short)f2bf(srcWh1[(size_t)(kbase + e) * GG + cg]);
        }
        wi1r[kk][nt] = fa;
        wh1r[kk][nt] = fb;
      }
    }
  }
  __syncthreads();

  // elementwise ownership: first 256 threads -> (batch ebl, unit eu)
  const bool elem = (tid < 256);
  const int ebl = (tid & 255) >> 3;    // 0..31
  const int eu = tid & 7;              // 0..7
  const int ebg = g * BG + ebl;        // global batch row
  const int egu = ub * UPB + eu;       // global unit
  float c0 = 0.f, c1 = 0.f;
  const float4 b1v = *(const float4*)(b1p + egu * 4);

  const int arow = lane & 15;
  const int koff = (lane >> 4) * 8;
  const unsigned* myflags = flags + g * BPG + (lane & 31) * 4;

  // A row offsets (elements): this wave's K window is [w*128, w*128+128)
  const int ro0 = (g * BG + arow) * HH + w * 128 + koff;
  const int ro1 = (g * BG + 16 + arow) * HH + w * 128 + koff;

  // ---- gate-input software prefetch (idx -> P0p row), one tick ahead ----
  int v_pf = 0;
  float4 p_pf = make_float4(0.f, 0.f, 0.f, 0.f);
  if (elem) {
    v_pf = idx[ebg * TT];                                        // k = 0
    p_pf = *(const float4*)(P0p + ((size_t)v_pf * HH + egu) * 4);
  }

#define GLD(dst, addr)                                                         \
  asm volatile("global_load_dwordx4 %0, %1, off"                               \
               : "=&v"(dst) : "v"(addr));

#define ISSUE4(s)                                                              \
  GLD(ring[s][0], p00 + (s) * 32)                                              \
  GLD(ring[s][1], p01 + (s) * 32)                                              \
  GLD(ring[s][2], p10 + (s) * 32)                                              \
  GLD(ring[s][3], p11 + (s) * 32)

#define WAITV(n)                                                               \
  asm volatile("s_waitcnt vmcnt(" #n ")" ::: "memory");                        \
  __builtin_amdgcn_sched_barrier(0);

#define LDB(s, nt) (*(const short8*)(&wlds[w4 + (s)][nt][lane][0]))

#define MFMA_STAGE(s)                                                                      \
  a0[0][0] = __builtin_amdgcn_mfma_f32_16x16x32_bf16(ring[s][0], f0a, a0[0][0], 0, 0, 0);  \
  a0[0][1] = __builtin_amdgcn_mfma_f32_16x16x32_bf16(ring[s][0], f0b, a0[0][1], 0, 0, 0);  \
  a0[1][0] = __builtin_amdgcn_mfma_f32_16x16x32_bf16(ring[s][1], f0a, a0[1][0], 0, 0, 0);  \
  a0[1][1] = __builtin_amdgcn_mfma_f32_16x16x32_bf16(ring[s][1], f0b, a0[1][1], 0, 0, 0);  \
  a1[0][0] = __builtin_amdgcn_mfma_f32_16x16x32_bf16(ring[s][0], wi1r[s][0], a1[0][0], 0, 0, 0); \
  a1[0][1] = __builtin_amdgcn_mfma_f32_16x16x32_bf16(ring[s][0], wi1r[s][1], a1[0][1], 0, 0, 0); \
  a1[1][0] = __builtin_amdgcn_mfma_f32_16x16x32_bf16(ring[s][1], wi1r[s][0], a1[1][0], 0, 0, 0); \
  a1[1][1] = __builtin_amdgcn_mfma_f32_16x16x32_bf16(ring[s][1], wi1r[s][1], a1[1][1], 0, 0, 0); \
  a1[0][0] = __builtin_amdgcn_mfma_f32_16x16x32_bf16(ring[s][2], wh1r[s][0], a1[0][0], 0, 0, 0); \
  a1[0][1] = __builtin_amdgcn_mfma_f32_16x16x32_bf16(ring[s][2], wh1r[s][1], a1[0][1], 0, 0, 0); \
  a1[1][0] = __builtin_amdgcn_mfma_f32_16x16x32_bf16(ring[s][3], wh1r[s][0], a1[1][0], 0, 0, 0); \
  a1[1][1] = __builtin_amdgcn_mfma_f32_16x16x32_bf16(ring[s][3], wh1r[s][1], a1[1][1], 0, 0, 0);

#define STAGE(s, WN)                                                           \
  WAITV(WN)                                                                    \
  {                                                                            \
    const short8 n0a = LDB(((s) + 1) & 3, 0);                                  \
    const short8 n0b = LDB(((s) + 1) & 3, 1);                                  \
    MFMA_STAGE(s)                                                              \
    f0a = n0a; f0b = n0b;                                                      \
  }

  for (int k = 0; k <= TT; ++k) {
    const unsigned short* A01 = h0r + (size_t)k * (BB * HH);                 // h0(k-1)
    const unsigned short* A2  = hs + (size_t)(k > 0 ? (k - 1) : 0) * (BB * HH); // h1(k-2)

    const unsigned short* p00 = A01 + ro0;
    const unsigned short* p01 = A01 + ro1;
    const unsigned short* p10 = A2 + ro0;
    const unsigned short* p11 = A2 + ro1;

    f32x4 a0[2][2], a1[2][2];
#pragma unroll
    for (int mt = 0; mt < 2; ++mt)
#pragma unroll
      for (int nt = 0; nt < 2; ++nt) {
        a0[mt][nt] = f32x4{0.f, 0.f, 0.f, 0.f};
        a1[mt][nt] = f32x4{0.f, 0.f, 0.f, 0.f};
      }

    short8 ring[4][4];
    short8 f0a = LDB(0, 0), f0b = LDB(0, 1);

    // 16 A-loads in flight (cached; XCD-L2 amortizes), counted drains
    ISSUE4(0) ISSUE4(1) ISSUE4(2) ISSUE4(3)
    STAGE(0, 12)
    STAGE(1, 8)
    STAGE(2, 4)
    STAGE(3, 0)

    // ---- both layers' K-partials -> LDS ----
    {
      const int colb = lane & 15;
      const int r0w = (lane >> 4) * 4;
#pragma unroll
      for (int mt = 0; mt < 2; ++mt)
#pragma unroll
        for (int nt = 0; nt < 2; ++nt)
#pragma unroll
          for (int r = 0; r < 4; ++r) {
            zbuf[0][w][mt * 16 + r0w + r][nt * 16 + colb] = a0[mt][nt][r];
            zbuf[1][w][mt * 16 + r0w + r][nt * 16 + colb] = a1[mt][nt][r];
          }
    }
    __syncthreads();

    if (elem) {
      // ---- layer 0 reduce + gates + h0 store ----
      float z0[4] = {0.f, 0.f, 0.f, 0.f};
      float z1[4] = {0.f, 0.f, 0.f, 0.f};
#pragma unroll
      for (int ww = 0; ww < 8; ++ww) {
        const float4 p0v = *(const float4*)(&zbuf[0][ww][ebl][eu * 4]);
        const float4 p1v = *(const float4*)(&zbuf[1][ww][ebl][eu * 4]);
        z0[0] += p0v.x; z0[1] += p0v.y; z0[2] += p0v.z; z0[3] += p0v.w;
        z1[0] += p1v.x; z1[1] += p1v.y; z1[2] += p1v.z; z1[3] += p1v.w;
      }
      if (k < TT) {
        const float gi = sigf(z0[0] + p_pf.x);
        const float gf = sigf(z0[1] + p_pf.y);
        const float gc = tanhfast(z0[2] + p_pf.z);
        const float go = sigf(z0[3] + p_pf.w);
        c0 = gf * c0 + gi * gc;
        __hip_atomic_store(&h0r[(size_t)(k + 1) * (BB * HH) + ebg * HH + egu],
                           f2bf(go * tanhfast(c0)),
                           __ATOMIC_RELAXED, __HIP_MEMORY_SCOPE_AGENT);
        if (k + 1 < TT) {   // prefetch next tick's gate inputs
          v_pf = idx[ebg * TT + k + 1];
          p_pf = *(const float4*)(P0p + ((size_t)v_pf * HH + egu) * 4);
        }
      }
      // ---- layer 1 reduce + gates + h1 store ----
      if (k > 0) {
        const float gi = sigf(z1[0] + b1v.x);
        const float gf = sigf(z1[1] + b1v.y);
        const float gc = tanhfast(z1[2] + b1v.z);
        const float go = sigf(z1[3] + b1v.w);
        c1 = gf * c1 + gi * gc;
        __hip_atomic_store(&hs[(size_t)k * (BB * HH) + ebg * HH + egu],
                           f2bf(go * tanhfast(c1)),
                           __ATOMIC_RELAXED, __HIP_MEMORY_SCOPE_AGENT);
      }
    }

    if (k == TT) break;  // proj_kernel consumes last store via dispatch fence

    // ---- group-local distributed-flag barrier ----
    __syncthreads();     // each wave drains vmcnt(0): h stores visible (L3)
    if (w == 0) {
      const unsigned tgt = (unsigned)(k + 1);
      if (lane == 0)
        __hip_atomic_store(&flags[g * BPG + ub], tgt,
                           __ATOMIC_RELAXED, __HIP_MEMORY_SCOPE_AGENT);
      for (;;) {
        int ok = 1;
        if (lane < 32) {
          uint32x4 f;
          asm volatile("global_load_dwordx4 %0, %1, off sc0 sc1\n\t"
                       "s_waitcnt vmcnt(0)"
                       : "=&v"(f) : "v"(myflags) : "memory");
          ok = (f[0] >= tgt) & (f[1] >= tgt) & (f[2] >= tgt) & (f[3] >= tgt);
        }
        if (__all(ok)) break;
        __builtin_amdgcn_s_sleep(2);
      }
    }
    __syncthreads();
  }
#undef GLD
#undef ISSUE4
#undef WAITV
#undef LDB
#undef MFMA_STAGE
#undef STAGE
}

// ---------------------------------------------------------------------------
// Final projection: logits[b][t][v] = hs1[b][t][:] @ Wproj.  One block per t.
// ---------------------------------------------------------------------------
__global__ void __launch_bounds__(256, 1)
proj_kernel(const unsigned short* __restrict__ hs, const unsigned short* __restrict__ Wppk,
            float* __restrict__ out)
{
  __shared__ short blds[16][64][8];  // 16 KB: one kt-slice of packed Wproj
  const int tid = threadIdx.x;
  const int lane = tid & 63;
  const int w = tid >> 6;
  const int t = blockIdx.x;
  const unsigned short* A = hs + (size_t)(t + 1) * (BB * HH);
  f32x4 acc[16];
#pragma unroll
  for (int nt = 0; nt < 16; ++nt) acc[nt] = f32x4{0.f, 0.f, 0.f, 0.f};
  const int arow = w * 16 + (lane & 15);
  const int koff = (lane >> 4) * 8;
  for (int kt = 0; kt < 32; ++kt) {
    __syncthreads();
    for (int i = tid; i < 16 * 64; i += 256)
      *(short8*)(&blds[i >> 6][i & 63][0]) =
          *(const short8*)(Wppk + (size_t)(((i >> 6) * 32 + kt) * 64 + (i & 63)) * 8);
    __syncthreads();
    const short8 a = *(const short8*)(A + arow * HH + kt * 32 + koff);
#pragma unroll
    for (int nt = 0; nt < 16; ++nt) {
      const short8 bf = *(const short8*)(&blds[nt][lane][0]);
      acc[nt] = __builtin_amdgcn_mfma_f32_16x16x32_bf16(a, bf, acc[nt], 0, 0, 0);
    }
  }
#pragma unroll
  for (int nt = 0; nt < 16; ++nt) {
#pragma unroll
    for (int r = 0; r < 4; ++r) {
      const int bbv = w * 16 + (lane >> 4) * 4 + r;
      const int vv = nt * 16 + (lane & 15);
      out[((size_t)bbv * TT + t) * VV + vv] = acc[nt][r];
    }
  }
}

// ---------------------------------------------------------------------------
extern "C" void kernel_launch(void* const* d_in, const int* in_sizes, int n_in,
                              void* d_out, int out_size, void* d_ws, size_t ws_size,
                              hipStream_t stream)
{
  (void)in_sizes; (void)n_in; (void)out_size; (void)ws_size;
  const int* idx = (const int*)d_in[0];
  const float* embed = (const float*)d_in[1];
  const float* Wi = (const float*)d_in[2];
  const float* Wh = (const float*)d_in[3];
  const float* bias = (const float*)d_in[4];
  const float* Wproj = (const float*)d_in[5];
  float* out = (float*)d_out;

  char* ws = (char*)d_ws;
  size_t off = 0;
  unsigned* flags = (unsigned*)(ws + off);          off += 1024;                      // 256 u32
  unsigned short* h0r = (unsigned short*)(ws + off); off += 513ull * BB * HH * 2;     // ~64.1 MB (rotating h0)
  unsigned short* hs = (unsigned short*)(ws + off);  off += 513ull * BB * HH * 2;     // ~64.1 MB
  float* P0p = (float*)(ws + off);                  off += 256ull * HH * 4 * 4;       // 4 MB
  unsigned short* Wppk = (unsigned short*)(ws + off); off += 16ull * 32 * 64 * 8 * 2; // 512 KB
  float* b1p = (float*)(ws + off);                  off += 4096ull * 4;

  hipMemsetAsync(flags, 0, 1024, stream);
  hipMemsetAsync(h0r, 0, (size_t)BB * HH * 2, stream);  // h0 slot 0 = h0(-1) = 0
  hipMemsetAsync(hs, 0, (size_t)BB * HH * 2, stream);   // hs slot 0 = h1(-1) = 0

  p0_kernel<<<256, 256, 0, stream>>>(embed, Wi, bias, P0p);
  pack_misc<<<128, 256, 0, stream>>>(Wproj, bias, Wppk, b1p);

  lstm_persist<<<NBLK, 512, 0, stream>>>(Wi, Wh, idx, P0p, b1p, h0r, hs, flags);

  proj_kernel<<<512, 256, 0, stream>>>(hs, Wppk, out);
}

// Round 13
// 3302.654 us; speedup vs baseline: 1.4052x; 1.3560x over previous
//
#include <hip/hip_runtime.h>

#define BB 64
#define HH 1024
#define TT 512
#define GG 4096
#define VV 256
#define NBLK 256
#define BPG 128   // blocks per group
#define BG  32    // batches per group
#define UPB 8     // units per block
#define SLOT (BB * HH)        // 65536 elements per h slot
#define GREG 32768            // elements per group region within a slot

typedef __attribute__((ext_vector_type(8))) short short8;
typedef __attribute__((ext_vector_type(4))) float f32x4;
typedef __attribute__((ext_vector_type(4))) unsigned uint32x4;

__device__ __forceinline__ unsigned short f2bf(float f) {
  unsigned u = __float_as_uint(f);
  u += 0x7fffu + ((u >> 16) & 1u);
  return (unsigned short)(u >> 16);
}

__device__ __forceinline__ float sigf(float x) { return 1.0f / (1.0f + __expf(-x)); }
__device__ __forceinline__ float tanhfast(float x) {
  float t = __expf(2.0f * x);
  return (t - 1.0f) / (t + 1.0f);
}

// ---------------------------------------------------------------------------
// Prepass 1: P0[v][unit][gate] = (embed @ Wi[0] + b[0]) re-packed, fp32.
// ---------------------------------------------------------------------------
__global__ void __launch_bounds__(256, 1)
p0_kernel(const float* __restrict__ embed, const float* __restrict__ Wi,
          const float* __restrict__ bias, float* __restrict__ P0p)
{
  __shared__ float elds[16][1024];  // 64 KB
  const int tid = threadIdx.x;
  const int vt = blockIdx.x >> 4;
  const int ct = blockIdx.x & 15;
  for (int i = tid; i < 16 * 1024; i += 256)
    elds[i >> 10][i & 1023] = embed[((vt * 16 + (i >> 10)) << 10) + (i & 1023)];
  __syncthreads();
  const int c = ct * 256 + tid;           // column in [0,4096)
  float acc[16];
#pragma unroll
  for (int v = 0; v < 16; ++v) acc[v] = 0.f;
  for (int kk = 0; kk < 1024; ++kk) {
    const float wv = Wi[kk * GG + c];     // coalesced
#pragma unroll
    for (int v = 0; v < 16; ++v) acc[v] = fmaf(elds[v][kk], wv, acc[v]);
  }
  const int u = c & 1023, g = c >> 10;
  const float bv = bias[c];               // b[0][c]
#pragma unroll
  for (int v = 0; v < 16; ++v)
    P0p[(((size_t)(vt * 16 + v) * HH) + u) * 4 + g] = acc[v] + bv;
}

// ---------------------------------------------------------------------------
// Prepass 2: pack Wproj into bf16 MFMA B-fragments; pack b[1] as [unit][gate].
// ---------------------------------------------------------------------------
__global__ void pack_misc(const float* __restrict__ Wproj, const float* __restrict__ bias,
                          unsigned short* __restrict__ Wppk, float* __restrict__ b1p)
{
  const int t = blockIdx.x * 256 + threadIdx.x;
  if (t < 16 * 32 * 64) {
    const int lane = t & 63;
    const int kt = (t >> 6) & 31;
    const int nt = t >> 11;
    const int v = nt * 16 + (lane & 15);
    const int kb = kt * 32 + (lane >> 4) * 8;
    short8 fr;
#pragma unroll
    for (int e = 0; e < 8; ++e)
      fr[e] = (short)f2bf(Wproj[(size_t)(kb + e) * VV + v]);
    *(short8*)(Wppk + (size_t)t * 8) = fr;
  }
  if (t < 4096)
    b1p[t] = bias[GG + (t & 3) * HH + (t >> 2)];  // b1p[u*4+g] = b[1][g*1024+u]
}

// ---------------------------------------------------------------------------
// Persistent LSTM kernel, 2 decoupled batch-groups.
// h slots use a REGIONED layout: slot[k][g][ub][b_local][u_local] — each
// block's 512 B of h output is contiguous, written by wave 0 as full-line
// single-producer write-through stores (no cross-XCD partial-line combining
// at the MALL). Consumers read with plain cached loads (XCD-L2 combines the
// group broadcast; slots rotate write-once so no stale-copy hazard).
// Group-local distributed-flag barrier (r9's best-measured design).
// ---------------------------------------------------------------------------
__global__ void __launch_bounds__(256, 1)
lstm_persist(const float* __restrict__ Wi, const float* __restrict__ Wh,
             const int* __restrict__ idx, const float* __restrict__ P0p,
             const float* __restrict__ b1p,
             unsigned short* __restrict__ h0r, unsigned short* __restrict__ hs,
             unsigned* __restrict__ flags)
{
  __shared__ short wlds[32][2][64][8];      // 64 KB: Wh0 [kt][nt][lane][8]
  __shared__ float zbuf[2][4][32][36];      // 36 KB: [layer][wave][row][col+pad]
  __shared__ unsigned short hstage[2][256]; // 1 KB: staged h0/h1 for wave-0 store

  const int tid = threadIdx.x;
  const int lane = tid & 63;
  const int w = tid >> 6;
  const int bid = blockIdx.x;
  const int g = bid & 1;          // group (~XCD parity)
  const int ub = bid >> 1;        // unit-block 0..127
  const int w8 = w * 8;

  // ---- one-time: Wh0 fragments -> LDS; Wi1, Wh1 fragments -> VGPRs ----
  short8 wi1r[8][2], wh1r[8][2];
  {
    const int arow16 = lane & 15;
    const int kb4 = (lane >> 4) * 8;
    for (int kk = 0; kk < 8; ++kk) {
      const int kbase = (w8 + kk) * 32 + kb4;
      for (int nt = 0; nt < 2; ++nt) {
        const int cl = nt * 16 + arow16;
        const int cg = (cl & 3) * HH + ub * UPB + (cl >> 2);
        short8 fr;
#pragma unroll
        for (int e = 0; e < 8; ++e)
          fr[e] = (short)f2bf(Wh[(size_t)(kbase + e) * GG + cg]);
        *(short8*)(&wlds[w8 + kk][nt][lane][0]) = fr;
      }
    }
    const float* srcWi1 = Wi + (size_t)HH * GG;
    const float* srcWh1 = Wh + (size_t)HH * GG;
#pragma unroll
    for (int kk = 0; kk < 8; ++kk) {
      const int kbase = (w8 + kk) * 32 + kb4;
#pragma unroll
      for (int nt = 0; nt < 2; ++nt) {
        const int cl = nt * 16 + arow16;
        const int cg = (cl & 3) * HH + ub * UPB + (cl >> 2);
        short8 fa, fb;
#pragma unroll
        for (int e = 0; e < 8; ++e) {
          fa[e] = (short)f2bf(srcWi1[(size_t)(kbase + e) * GG + cg]);
          fb[e] = (short)f2bf(srcWh1[(size_t)(kbase + e) * GG + cg]);
        }
        wi1r[kk][nt] = fa;
        wh1r[kk][nt] = fb;
      }
    }
  }
  __syncthreads();

  // elementwise ownership: thread -> (group-local batch ebl, local unit eu)
  const int ebl = tid >> 3;            // 0..31
  const int eu = tid & 7;              // 0..7
  const int ebg = g * BG + ebl;        // global batch row
  const int egu = ub * UPB + eu;       // global unit
  float c0 = 0.f, c1 = 0.f;
  const float4 b1v = *(const float4*)(b1p + egu * 4);

  const int arow = lane & 15;
  const unsigned* myflags = flags + g * BPG + (lane & 31) * 4;

  // regioned A offsets (elements within a slot):
  //   kt tile s of wave w -> region (w8+s)*4 + (lane>>4), batch arow (mt0)
  //   element off = g*GREG + (w8+s)*1024 + (lane>>4)*256 + arow*8; mt1 = +128
  const int ro0 = g * GREG + w8 * 1024 + (lane >> 4) * 256 + arow * 8;
  const int ro1 = ro0 + 128;

  // ---- gate-input software prefetch (idx -> P0p row), one tick ahead ----
  int v_pf = idx[ebg * TT];                                        // k = 0
  float4 p_pf = *(const float4*)(P0p + ((size_t)v_pf * HH + egu) * 4);

#define GLD(dst, addr)                                                         \
  asm volatile("global_load_dwordx4 %0, %1, off"                               \
               : "=&v"(dst) : "v"(addr));

#define ISSUE4(s)                                                              \
  GLD(ring[s][0], p00 + (s) * 1024)                                            \
  GLD(ring[s][1], p01 + (s) * 1024)                                            \
  GLD(ring[s][2], p10 + (s) * 1024)                                            \
  GLD(ring[s][3], p11 + (s) * 1024)

#define WAITV(n)                                                               \
  asm volatile("s_waitcnt vmcnt(" #n ")" ::: "memory");                        \
  __builtin_amdgcn_sched_barrier(0);

#define LDB(s, nt) (*(const short8*)(&wlds[w8 + (s)][nt][lane][0]))

#define MFMA_STAGE(s)                                                                      \
  a0[0][0] = __builtin_amdgcn_mfma_f32_16x16x32_bf16(ring[s][0], f0a, a0[0][0], 0, 0, 0);  \
  a0[0][1] = __builtin_amdgcn_mfma_f32_16x16x32_bf16(ring[s][0], f0b, a0[0][1], 0, 0, 0);  \
  a0[1][0] = __builtin_amdgcn_mfma_f32_16x16x32_bf16(ring[s][1], f0a, a0[1][0], 0, 0, 0);  \
  a0[1][1] = __builtin_amdgcn_mfma_f32_16x16x32_bf16(ring[s][1], f0b, a0[1][1], 0, 0, 0);  \
  a1[0][0] = __builtin_amdgcn_mfma_f32_16x16x32_bf16(ring[s][0], wi1r[s][0], a1[0][0], 0, 0, 0); \
  a1[0][1] = __builtin_amdgcn_mfma_f32_16x16x32_bf16(ring[s][0], wi1r[s][1], a1[0][1], 0, 0, 0); \
  a1[1][0] = __builtin_amdgcn_mfma_f32_16x16x32_bf16(ring[s][1], wi1r[s][0], a1[1][0], 0, 0, 0); \
  a1[1][1] = __builtin_amdgcn_mfma_f32_16x16x32_bf16(ring[s][1], wi1r[s][1], a1[1][1], 0, 0, 0); \
  a1[0][0] = __builtin_amdgcn_mfma_f32_16x16x32_bf16(ring[s][2], wh1r[s][0], a1[0][0], 0, 0, 0); \
  a1[0][1] = __builtin_amdgcn_mfma_f32_16x16x32_bf16(ring[s][2], wh1r[s][1], a1[0][1], 0, 0, 0); \
  a1[1][0] = __builtin_amdgcn_mfma_f32_16x16x32_bf16(ring[s][3], wh1r[s][0], a1[1][0], 0, 0, 0); \
  a1[1][1] = __builtin_amdgcn_mfma_f32_16x16x32_bf16(ring[s][3], wh1r[s][1], a1[1][1], 0, 0, 0);

#define STAGE(s, WN)                                                           \
  WAITV(WN)                                                                    \
  {                                                                            \
    const short8 n0a = LDB(((s) + 1) & 7, 0);                                  \
    const short8 n0b = LDB(((s) + 1) & 7, 1);                                  \
    MFMA_STAGE(s)                                                              \
    f0a = n0a; f0b = n0b;                                                      \
  }

  for (int k = 0; k <= TT; ++k) {
    const unsigned short* A01 = h0r + (size_t)k * SLOT;                 // h0(k-1)
    const unsigned short* A2  = hs + (size_t)(k > 0 ? (k - 1) : 0) * SLOT; // h1(k-2)

    const unsigned short* p00 = A01 + ro0;
    const unsigned short* p01 = A01 + ro1;
    const unsigned short* p10 = A2 + ro0;
    const unsigned short* p11 = A2 + ro1;

    f32x4 a0[2][2], a1[2][2];
#pragma unroll
    for (int mt = 0; mt < 2; ++mt)
#pragma unroll
      for (int nt = 0; nt < 2; ++nt) {
        a0[mt][nt] = f32x4{0.f, 0.f, 0.f, 0.f};
        a1[mt][nt] = f32x4{0.f, 0.f, 0.f, 0.f};
      }

    short8 ring[8][4];
    short8 f0a = LDB(0, 0), f0b = LDB(0, 1);

    // all 32 A-loads in flight (cached path; XCD-L2 amortizes the broadcast)
    ISSUE4(0) ISSUE4(1) ISSUE4(2) ISSUE4(3)
    ISSUE4(4) ISSUE4(5) ISSUE4(6) ISSUE4(7)
    STAGE(0, 28)
    STAGE(1, 24)
    STAGE(2, 20)
    STAGE(3, 16)
    STAGE(4, 12)
    STAGE(5, 8)
    STAGE(6, 4)
    STAGE(7, 0)

    // ---- both layers' K-partials -> LDS ----
    {
      const int colb = lane & 15;
      const int r0w = (lane >> 4) * 4;
#pragma unroll
      for (int mt = 0; mt < 2; ++mt)
#pragma unroll
        for (int nt = 0; nt < 2; ++nt)
#pragma unroll
          for (int r = 0; r < 4; ++r) {
            zbuf[0][w][mt * 16 + r0w + r][nt * 16 + colb] = a0[mt][nt][r];
            zbuf[1][w][mt * 16 + r0w + r][nt * 16 + colb] = a1[mt][nt][r];
          }
    }
    __syncthreads();

    // ---- layer 0 reduce + gates -> hstage ----
    {
      float z0[4] = {0.f, 0.f, 0.f, 0.f};
#pragma unroll
      for (int ww = 0; ww < 4; ++ww) {
        const float4 pv = *(const float4*)(&zbuf[0][ww][ebl][eu * 4]);
        z0[0] += pv.x; z0[1] += pv.y; z0[2] += pv.z; z0[3] += pv.w;
      }
      if (k < TT) {
        const float gi = sigf(z0[0] + p_pf.x);
        const float gf = sigf(z0[1] + p_pf.y);
        const float gc = tanhfast(z0[2] + p_pf.z);
        const float go = sigf(z0[3] + p_pf.w);
        c0 = gf * c0 + gi * gc;
        hstage[0][ebl * 8 + eu] = f2bf(go * tanhfast(c0));
        if (k + 1 < TT) {   // prefetch next tick's gate inputs
          v_pf = idx[ebg * TT + k + 1];
          p_pf = *(const float4*)(P0p + ((size_t)v_pf * HH + egu) * 4);
        }
      }
    }
    // ---- layer 1 reduce + gates -> hstage ----
    if (k > 0) {
      float z1[4] = {0.f, 0.f, 0.f, 0.f};
#pragma unroll
      for (int ww = 0; ww < 4; ++ww) {
        const float4 pv = *(const float4*)(&zbuf[1][ww][ebl][eu * 4]);
        z1[0] += pv.x; z1[1] += pv.y; z1[2] += pv.z; z1[3] += pv.w;
      }
      const float gi = sigf(z1[0] + b1v.x);
      const float gf = sigf(z1[1] + b1v.y);
      const float gc = tanhfast(z1[2] + b1v.z);
      const float go = sigf(z1[3] + b1v.w);
      c1 = gf * c1 + gi * gc;
      hstage[1][ebl * 8 + eu] = f2bf(go * tanhfast(c1));
    }
    __syncthreads();   // hstage complete; also protects zbuf

    // ---- wave 0: coalesced single-producer full-line write-through ----
    if (w == 0) {
      const bool do0 = (lane < 32) && (k < TT);       // h0 -> slot k+1
      const bool do1 = (lane >= 32) && (k > 0);       // h1 -> slot k
      unsigned short* dst =
          (lane < 32)
              ? (h0r + (size_t)(k + 1) * SLOT + g * GREG + ub * 256 + lane * 8)
              : (hs + (size_t)k * SLOT + g * GREG + ub * 256 + (lane - 32) * 8);
      if (do0 | do1) {
        const uint32x4 val =
            *(const uint32x4*)&hstage[lane >> 5][(lane & 31) * 8];
        asm volatile("global_store_dwordx4 %0, %1, off sc0 sc1"
                     :: "v"(dst), "v"(val) : "memory");
      }
      asm volatile("s_waitcnt vmcnt(0)" ::: "memory");  // stores visible (L3)
    }

    if (k == TT) break;  // proj_kernel consumes last store via dispatch fence

    // ---- group-local distributed-flag barrier ----
    if (w == 0) {
      const unsigned tgt = (unsigned)(k + 1);
      if (lane == 0)
        __hip_atomic_store(&flags[g * BPG + ub], tgt,
                           __ATOMIC_RELAXED, __HIP_MEMORY_SCOPE_AGENT);
      for (;;) {
        int ok = 1;
        if (lane < 32) {
          uint32x4 f;
          asm volatile("global_load_dwordx4 %0, %1, off sc0 sc1\n\t"
                       "s_waitcnt vmcnt(0)"
                       : "=&v"(f) : "v"(myflags) : "memory");
          ok = (f[0] >= tgt) & (f[1] >= tgt) & (f[2] >= tgt) & (f[3] >= tgt);
        }
        if (__all(ok)) break;
        __builtin_amdgcn_s_sleep(2);
      }
    }
    __syncthreads();
  }
#undef GLD
#undef ISSUE4
#undef WAITV
#undef LDB
#undef MFMA_STAGE
#undef STAGE
}

// ---------------------------------------------------------------------------
// Final projection: logits[b][t][v] = hs1[b][t][:] @ Wproj.  One block per t.
// Reads hs in the regioned layout.
// ---------------------------------------------------------------------------
__global__ void __launch_bounds__(256, 1)
proj_kernel(const unsigned short* __restrict__ hs, const unsigned short* __restrict__ Wppk,
            float* __restrict__ out)
{
  __shared__ short blds[16][64][8];  // 16 KB: one kt-slice of packed Wproj
  const int tid = threadIdx.x;
  const int lane = tid & 63;
  const int w = tid >> 6;
  const int t = blockIdx.x;
  const unsigned short* A = hs + (size_t)(t + 1) * SLOT;
  f32x4 acc[16];
#pragma unroll
  for (int nt = 0; nt < 16; ++nt) acc[nt] = f32x4{0.f, 0.f, 0.f, 0.f};
  const int brow = w * 16 + (lane & 15);          // batch 0..63
  const int gp = brow >> 5;
  const int bl = brow & 31;
  // regioned: elem off = gp*GREG + kt*1024 + (lane>>4)*256 + bl*8
  const int aoff = gp * GREG + (lane >> 4) * 256 + bl * 8;
  for (int kt = 0; kt < 32; ++kt) {
    __syncthreads();
    for (int i = tid; i < 16 * 64; i += 256)
      *(short8*)(&blds[i >> 6][i & 63][0]) =
          *(const short8*)(Wppk + (size_t)(((i >> 6) * 32 + kt) * 64 + (i & 63)) * 8);
    __syncthreads();
    const short8 a = *(const short8*)(A + aoff + kt * 1024);
#pragma unroll
    for (int nt = 0; nt < 16; ++nt) {
      const short8 bf = *(const short8*)(&blds[nt][lane][0]);
      acc[nt] = __builtin_amdgcn_mfma_f32_16x16x32_bf16(a, bf, acc[nt], 0, 0, 0);
    }
  }
#pragma unroll
  for (int nt = 0; nt < 16; ++nt) {
#pragma unroll
    for (int r = 0; r < 4; ++r) {
      const int bbv = w * 16 + (lane >> 4) * 4 + r;
      const int vv = nt * 16 + (lane & 15);
      out[((size_t)bbv * TT + t) * VV + vv] = acc[nt][r];
    }
  }
}

// ---------------------------------------------------------------------------
extern "C" void kernel_launch(void* const* d_in, const int* in_sizes, int n_in,
                              void* d_out, int out_size, void* d_ws, size_t ws_size,
                              hipStream_t stream)
{
  (void)in_sizes; (void)n_in; (void)out_size; (void)ws_size;
  const int* idx = (const int*)d_in[0];
  const float* embed = (const float*)d_in[1];
  const float* Wi = (const float*)d_in[2];
  const float* Wh = (const float*)d_in[3];
  const float* bias = (const float*)d_in[4];
  const float* Wproj = (const float*)d_in[5];
  float* out = (float*)d_out;

  char* ws = (char*)d_ws;
  size_t off = 0;
  unsigned* flags = (unsigned*)(ws + off);          off += 1024;                      // 256 u32
  unsigned short* h0r = (unsigned short*)(ws + off); off += 513ull * SLOT * 2;        // ~64.1 MB (rotating h0)
  unsigned short* hs = (unsigned short*)(ws + off);  off += 513ull * SLOT * 2;        // ~64.1 MB
  float* P0p = (float*)(ws + off);                  off += 256ull * HH * 4 * 4;       // 4 MB
  unsigned short* Wppk = (unsigned short*)(ws + off); off += 16ull * 32 * 64 * 8 * 2; // 512 KB
  float* b1p = (float*)(ws + off);                  off += 4096ull * 4;

  hipMemsetAsync(flags, 0, 1024, stream);
  hipMemsetAsync(h0r, 0, (size_t)SLOT * 2, stream);  // h0 slot 0 = h0(-1) = 0
  hipMemsetAsync(hs, 0, (size_t)SLOT * 2, stream);   // hs slot 0 = h1(-1) = 0

  p0_kernel<<<256, 256, 0, stream>>>(embed, Wi, bias, P0p);
  pack_misc<<<128, 256, 0, stream>>>(Wproj, bias, Wppk, b1p);

  lstm_persist<<<NBLK, 256, 0, stream>>>(Wi, Wh, idx, P0p, b1p, h0r, hs, flags);

  proj_kernel<<<512, 256, 0, stream>>>(hs, Wppk, out);
}